// Round 1
// baseline (407.201 us; speedup 1.0000x reference)
//
#include <hip/hip_runtime.h>

// MaxPool2d: kernel 2x2, stride 2x2, VALID padding, NCHW fp32.
// x: (16, 96, 224, 224) -> y: (16, 96, 112, 112)
// Streaming, zero reuse. Traffic floor: 308.3 MB read + 77.1 MB write ~= 61 us
// at 6.3 TB/s achievable HBM BW.
//
// This revision: persistent grid-stride loop instead of 37,632 one-shot
// workgroups. Per-wg work was only ~10 KB of traffic (~0.4 us lifetime), so
// the command processor's workgroup dispatch rate (~ a few wg/cycle) was a
// plausible limiter/tail cost. grid = 2048 blocks (256 thr) = exact
// full-residency footprint (8 wg/CU x 256 CU); each thread iterates ~18x.
// Per-iteration memory pattern unchanged and fully coalesced:
//   - one dense fvec4 (dwordx4) load from input row 2*oh
//   - one dense fvec4 load from input row 2*oh+1
//   - one dense fvec2 (dwordx2) store
// All nontemporal (read-once / write-once streaming).

typedef float fvec4 __attribute__((ext_vector_type(4)));
typedef float fvec2 __attribute__((ext_vector_type(2)));

#define N_  16
#define C_  96
#define H_  224
#define W_  224
#define OH_ 112
#define OW_ 112
#define PAIRS_PER_ROW (OW_ / 2)   // 56

__global__ __launch_bounds__(256) void maxpool2d_k(
    const float* __restrict__ x, float* __restrict__ y, int total_pairs) {
    const int stride = gridDim.x * blockDim.x;   // 524,288 threads resident

    for (int t = blockIdx.x * blockDim.x + threadIdx.x; t < total_pairs;
         t += stride) {
        int p  = t % PAIRS_PER_ROW;        // pair index within output row
        int r  = t / PAIRS_PER_ROW;        // r = (n*C_ + c)*OH_ + oh
        int oh = r % OH_;
        int nc = r / OH_;

        const fvec4* row0 =
            (const fvec4*)(x + ((size_t)nc * H_ + (size_t)(2 * oh)) * W_) + p;
        const fvec4* row1 = row0 + (W_ / 4);

        fvec4 a = __builtin_nontemporal_load(row0);
        fvec4 b = __builtin_nontemporal_load(row1);

        fvec2 o;
        o.x = fmaxf(fmaxf(a.x, a.y), fmaxf(b.x, b.y));
        o.y = fmaxf(fmaxf(a.z, a.w), fmaxf(b.z, b.w));

        fvec2* dst = (fvec2*)(y + (size_t)r * OW_) + p;
        __builtin_nontemporal_store(o, dst);
    }
}

extern "C" void kernel_launch(void* const* d_in, const int* in_sizes, int n_in,
                              void* d_out, int out_size, void* d_ws, size_t ws_size,
                              hipStream_t stream) {
    const float* x = (const float*)d_in[0];
    float* y = (float*)d_out;

    const int total_pairs = N_ * C_ * OH_ * PAIRS_PER_ROW;  // 9,633,792
    const int block = 256;
    // Full-residency persistent grid: 8 blocks/CU x 256 CUs.
    const int grid = 2048;

    maxpool2d_k<<<grid, block, 0, stream>>>(x, y, total_pairs);
}